// Round 10
// baseline (164.534 us; speedup 1.0000x reference)
//
#include <hip/hip_runtime.h>
#include <hip/hip_bf16.h>
#include <stdint.h>

#define BATCH 4
#define SEQ   1024
#define DMODEL 1024
#define NH    16
#define DV    64

typedef short bf8 __attribute__((ext_vector_type(8)));   // 8 bf16 raw bits = 4 VGPRs
typedef float f4  __attribute__((ext_vector_type(4)));

static __device__ __forceinline__ short f2bf(float f) {
    union { float f; uint32_t u; } a; a.f = f;
    uint32_t r = a.u + 0x7FFF + ((a.u >> 16) & 1);   // RNE
    return (short)(r >> 16);
}

static __device__ __forceinline__ f4 mfma16(bf8 a, bf8 b, f4 c) {
    return __builtin_amdgcn_mfma_f32_16x16x32_bf16(a, b, c, 0, 0, 0);
}

// async global->LDS, 16B per lane; LDS dest is wave-uniform base + lane*16
static __device__ __forceinline__ void gload16(const short* g, short* l) {
    __builtin_amdgcn_global_load_lds((const __attribute__((address_space(1))) void*)g,
                                     (__attribute__((address_space(3))) void*)l,
                                     16, 0, 0);
}

// ---------------- conversion kernels ----------------

__global__ void cvt_x_kernel(const float* __restrict__ x, short* __restrict__ xb) {
    int i = blockIdx.x * blockDim.x + threadIdx.x;   // one short4 per thread
    float4 v = ((const float4*)x)[i];
    short4 o;
    o.x = f2bf(v.x); o.y = f2bf(v.y); o.z = f2bf(v.z); o.w = f2bf(v.w);
    ((short4*)xb)[i] = o;
}

// fused: z=0 w_q -> wqkvt[0:1024], z=1 w_kv -> wqkvt[1024:2048], z=2 w_o -> wot
__global__ void transpose_w_kernel(const float* __restrict__ wq, const float* __restrict__ wkv,
                                   const float* __restrict__ wo,
                                   short* __restrict__ wqkvt, short* __restrict__ wot) {
    __shared__ float tile[32][33];
    int z = blockIdx.z;
    const float* w = (z == 0) ? wq : (z == 1) ? wkv : wo;
    short* wt = (z == 0) ? wqkvt : (z == 1) ? (wqkvt + (1u << 20)) : wot;
    int bx = blockIdx.x, by = blockIdx.y;
    int tx = threadIdx.x, ty = threadIdx.y;          // block (32,8)
    #pragma unroll
    for (int i = 0; i < 4; i++)
        tile[ty + i * 8][tx] = w[(size_t)(by * 32 + ty + i * 8) * 1024 + bx * 32 + tx];
    __syncthreads();
    #pragma unroll
    for (int i = 0; i < 4; i++)
        wt[(size_t)(bx * 32 + ty + i * 8) * 1024 + by * 32 + tx] = f2bf(tile[tx][ty + i * 8]);
}

// ---------------- projection GEMM: xb (4096xK) * wqkvt^T, N=2048 --------------------
// BK=32 (m97-proven config), 128x128 tile. LDS XOR-swizzle: 16B seg c of row r at
// phys c^((r>>1)&3) -> frag ds_read_b128 aliases only 2 lanes/bank (free, m136).
// Epilogue: n<1024 -> q' (scaled, kw folded); n>=1024 -> kv row-major AND kvT via
// LDS transpose (reuses staging LDS, coalesced 16B stores).

__global__ __launch_bounds__(256) void gemm_proj_kernel(
    const short* __restrict__ A, const short* __restrict__ Bt,
    const float* __restrict__ kw,
    short* __restrict__ q_out, short* __restrict__ kv_out, short* __restrict__ kvT_out)
{
    __shared__ short SM[8704];       // As[0:4096] | Bs[4096:8192]; reused as T[64*136]
    short* As = SM;
    short* Bs = SM + 4096;
    const int K = DMODEL;

    int tid = threadIdx.x;
    int wave = tid >> 6, lane = tid & 63;
    int quad = lane >> 4, l16 = lane & 15;
    int m0 = blockIdx.y * 128;
    int n0 = blockIdx.x * 128;
    int wm = (wave >> 1) * 64;
    int wn = (wave & 1) * 64;
    int fsw = (l16 >> 1) & 3;        // frag-read segment xor

    f4 acc[4][4] = {};

    for (int k0 = 0; k0 < K; k0 += 32) {
        __syncthreads();
        #pragma unroll
        for (int c = 0; c < 2; c++) {
            int flat = c * 256 + tid;                  // 0..511
            int row = flat >> 2;                       // 0..127
            int seg = (flat & 3) ^ ((row >> 1) & 3);   // swizzled global segment
            gload16(A  + (size_t)(m0 + row) * K + k0 + seg * 8, As + flat * 8);
            gload16(Bt + (size_t)(n0 + row) * K + k0 + seg * 8, Bs + flat * 8);
        }
        __syncthreads();

        bf8 af[4], bfr[4];
        #pragma unroll
        for (int i = 0; i < 4; i++)
            af[i] = *(const bf8*)(As + (wm + i * 16 + l16) * 32 + (quad ^ fsw) * 8);
        #pragma unroll
        for (int j = 0; j < 4; j++)
            bfr[j] = *(const bf8*)(Bs + (wn + j * 16 + l16) * 32 + (quad ^ fsw) * 8);
        #pragma unroll
        for (int i = 0; i < 4; i++)
            #pragma unroll
            for (int j = 0; j < 4; j++)
                acc[i][j] = mfma16(af[i], bfr[j], acc[i][j]);
    }

    // ---- direct epilogue: q' / kv row-major ----
    #pragma unroll
    for (int i = 0; i < 4; i++) {
        #pragma unroll
        for (int j = 0; j < 4; j++) {
            int n = n0 + wn + j * 16 + l16;
            int mb = m0 + wm + i * 16 + quad * 4;
            float v0 = acc[i][j][0], v1 = acc[i][j][1], v2 = acc[i][j][2], v3 = acc[i][j][3];
            if (n < 1024) {
                float kws = 0.03125f * (1.0f + kw[n]);
                q_out[(size_t)(mb + 0) * 1024 + n] = f2bf(v0 * kws);
                q_out[(size_t)(mb + 1) * 1024 + n] = f2bf(v1 * kws);
                q_out[(size_t)(mb + 2) * 1024 + n] = f2bf(v2 * kws);
                q_out[(size_t)(mb + 3) * 1024 + n] = f2bf(v3 * kws);
            } else {
                int n2 = n - 1024;
                kv_out[(size_t)(mb + 0) * 1024 + n2] = f2bf(v0);
                kv_out[(size_t)(mb + 1) * 1024 + n2] = f2bf(v1);
                kv_out[(size_t)(mb + 2) * 1024 + n2] = f2bf(v2);
                kv_out[(size_t)(mb + 3) * 1024 + n2] = f2bf(v3);
            }
        }
    }

    // ---- kvT via LDS transpose (kv column-blocks only; block-uniform condition) ----
    if (n0 >= 1024) {
        const int TST = 136;                // row stride (shorts): 272B, 16B-aligned rows
        short* T = SM;                      // reuse staging LDS (64*136 = 8704 exactly)
        int n2base = n0 - 1024;
        int mloc = m0 & 1023;               // column base within the 1024-long kvT row
        int bq = m0 >> 10;                  // batch index (uniform across the tile)
        #pragma unroll
        for (int hn = 0; hn < 2; hn++) {
            __syncthreads();                // staging reads / previous half done
            if ((wave & 1) == hn) {         // waves owning this 64-col half write T[n][m]
                #pragma unroll
                for (int i = 0; i < 4; i++) {
                    #pragma unroll
                    for (int j = 0; j < 4; j++) {
                        int nl = j * 16 + l16;                       // 0..63
                        int ml = wm + i * 16 + quad * 4;             // 0..127
                        short4 tv;
                        tv.x = f2bf(acc[i][j][0]); tv.y = f2bf(acc[i][j][1]);
                        tv.z = f2bf(acc[i][j][2]); tv.w = f2bf(acc[i][j][3]);
                        *(short4*)(T + nl * TST + ml) = tv;
                    }
                }
            }
            __syncthreads();
            // cooperative coalesced store: 64 rows x 128 m-shorts = 1024 x 16B
            #pragma unroll
            for (int c = 0; c < 4; c++) {
                int flat = c * 256 + tid;       // 0..1023
                int row = flat >> 4;            // 0..63
                int seg = flat & 15;            // 16B unit within row
                bf8 vseg = *(const bf8*)(T + row * TST + seg * 8);
                int n2 = n2base + hn * 64 + row;
                int bh = (bq << 4) + (n2 >> 6);
                *(bf8*)(kvT_out + (size_t)(bh * 64 + (n2 & 63)) * 1024 + mloc + seg * 8) = vseg;
            }
        }
    }
}

// ---------------- output GEMM: yb (4096xK) * wot^T, N=1024 --------------------------
// 64x128 tile, BK=32 -> 512 blocks (2/CU). Wave w owns rows wm=w*16, all 128 cols:
// 8 C-frags, 8 MFMAs per BK-32 iter. LDS 12 KB.

__global__ __launch_bounds__(256) void gemm_out_kernel(
    const short* __restrict__ A, const short* __restrict__ Bt,
    float* __restrict__ c_out)
{
    __shared__ short As[64 * 32];    // 4 KB
    __shared__ short Bs[128 * 32];   // 8 KB
    const int K = DMODEL;

    int tid = threadIdx.x;
    int wave = tid >> 6, lane = tid & 63;
    int quad = lane >> 4, l16 = lane & 15;
    int m0 = blockIdx.y * 64;
    int n0 = blockIdx.x * 128;
    int wm = wave * 16;
    int fsw = (l16 >> 1) & 3;

    f4 acc[8] = {};

    for (int k0 = 0; k0 < K; k0 += 32) {
        __syncthreads();
        {
            int flat = tid;                            // 0..255 -> A 64x32
            int row = flat >> 2;                       // 0..63
            int seg = (flat & 3) ^ ((row >> 1) & 3);
            gload16(A + (size_t)(m0 + row) * K + k0 + seg * 8, As + flat * 8);
        }
        #pragma unroll
        for (int c = 0; c < 2; c++) {
            int flat = c * 256 + tid;                  // 0..511 -> B 128x32
            int row = flat >> 2;                       // 0..127
            int seg = (flat & 3) ^ ((row >> 1) & 3);
            gload16(Bt + (size_t)(n0 + row) * K + k0 + seg * 8, Bs + flat * 8);
        }
        __syncthreads();

        bf8 af = *(const bf8*)(As + (wm + l16) * 32 + (quad ^ fsw) * 8);
        #pragma unroll
        for (int j = 0; j < 8; j++) {
            bf8 bf_ = *(const bf8*)(Bs + (j * 16 + l16) * 32 + (quad ^ fsw) * 8);
            acc[j] = mfma16(af, bf_, acc[j]);
        }
    }

    #pragma unroll
    for (int j = 0; j < 8; j++) {
        int n = n0 + j * 16 + l16;
        int mb = m0 + wm + quad * 4;
        c_out[(size_t)(mb + 0) * 1024 + n] = acc[j][0];
        c_out[(size_t)(mb + 1) * 1024 + n] = acc[j][1];
        c_out[(size_t)(mb + 2) * 1024 + n] = acc[j][2];
        c_out[(size_t)(mb + 3) * 1024 + n] = acc[j][3];
    }
}

// ---------------- flash attention (causal), pair-balanced, 2-wave blocks ------------
// blockIdx.x = x*2+half, x in [0,8): block handles 32-row halves of q-tiles A=x and
// B=15-x. Every block: 17 procs/wave over 16-x staged K/V tiles. 1024 blocks ->
// 4 blocks/CU (LDS 36.6 KB): 4 independent barrier domains per CU for stall overlap.
// K/V staged via global_load_lds (XOR-swizzled), double-buffered, 1 barrier/tile.
// exp without max-subtraction (logits bounded by construction); row-sums via MFMA
// vs all-ones; per-wave private P (no barrier).

#define PLD 72   // P row stride (shorts)

__global__ __launch_bounds__(128) void attn_kernel(
    const short* __restrict__ qg, const short* __restrict__ kvg,
    const short* __restrict__ kvTg, short* __restrict__ yg)
{
    int bh = blockIdx.y;
    int b = bh >> 4, h = bh & 15;
    int x = blockIdx.x >> 1;
    int half = blockIdx.x & 1;
    int tid = threadIdx.x;
    int wave = tid >> 6, lane = tid & 63;
    int quad = lane >> 4, l16 = lane & 15;
    int qa0 = x * 64 + half * 32;
    int qb0 = (15 - x) * 64 + half * 32;
    int ntiles = 16 - x;

    __shared__ short Ks[2][64 * 64];    // [key][ch], swizzled, 8 KB each
    __shared__ short Vs[2][64 * 64];    // [vcol][key], swizzled
    __shared__ short Ps[2][16 * PLD];
    short* myP = &Ps[wave][0];

    const short* qpa = qg + (size_t)(b * 1024 + qa0 + wave * 16 + l16) * 1024 + h * 64;
    const short* qpb = qg + (size_t)(b * 1024 + qb0 + wave * 16 + l16) * 1024 + h * 64;
    bf8 qa_0 = *(const bf8*)(qpa + quad * 8);
    bf8 qa_1 = *(const bf8*)(qpa + 32 + quad * 8);
    bf8 qb_0 = *(const bf8*)(qpb + quad * 8);
    bf8 qb_1 = *(const bf8*)(qpb + 32 + quad * 8);

    bf8 ones;
    #pragma unroll
    for (int j = 0; j < 8; j++) ones[j] = (short)0x3F80;   // bf16 1.0

    f4 oa[4] = {}, ob[4] = {};
    f4 lsa = {}, lsb = {};
    int rowbaseA = qa0 + wave * 16 + quad * 4;
    int rowbaseB = qb0 + wave * 16 + quad * 4;

    auto stage = [&](int jt) {
        short* dstK = &Ks[jt & 1][0];
        short* dstV = &Vs[jt & 1][0];
        int j0 = jt * 64;
        #pragma unroll
        for (int k = 0; k < 4; k++) {
            int flat = k * 128 + tid;          // 0..511
            int row = flat >> 3;
            int lseg = (flat & 7) ^ (row & 7);
            gload16(kvg + (size_t)(b * 1024 + j0 + row) * 1024 + h * 64 + lseg * 8,
                    dstK + flat * 8);
            gload16(kvTg + (size_t)(bh * 64 + row) * 1024 + j0 + lseg * 8,
                    dstV + flat * 8);
        }
    };

    auto proc = [&](bf8 qf0, bf8 qf1, int rowbase, int j0,
                    const short* K, const short* V, f4 (&o)[4], f4& lsum) {
        f4 s[4];
        #pragma unroll
        for (int c = 0; c < 4; c++) {
            int row = c * 16 + l16;
            int swz = row & 7;
            bf8 kb0 = *(const bf8*)(K + row * 64 + (quad ^ swz) * 8);
            bf8 kb1 = *(const bf8*)(K + row * 64 + (((quad + 4) ^ swz)) * 8);
            f4 t = {};
            t = mfma16(qf0, kb0, t);
            t = mfma16(qf1, kb1, t);
            s[c] = t;
        }
        #pragma unroll
        for (int r = 0; r < 4; r++) {
            int qi = rowbase + r;
            float p0 = (j0 + l16      <= qi) ? __expf(s[0][r]) : 0.0f;
            float p1 = (j0 + 16 + l16 <= qi) ? __expf(s[1][r]) : 0.0f;
            float p2 = (j0 + 32 + l16 <= qi) ? __expf(s[2][r]) : 0.0f;
            float p3 = (j0 + 48 + l16 <= qi) ? __expf(s[3][r]) : 0.0f;
            int prow = quad * 4 + r;
            myP[prow * PLD + l16]      = f2bf(p0);
            myP[prow * PLD + 16 + l16] = f2bf(p1);
            myP[prow * PLD + 32 + l16] = f2bf(p2);
            myP[prow * PLD + 48 + l16] = f2bf(p3);
        }
        bf8 pf0 = *(const bf8*)(myP + l16 * PLD + quad * 8);
        bf8 pf1 = *(const bf8*)(myP + l16 * PLD + 32 + quad * 8);
        lsum = mfma16(pf0, ones, lsum);
        lsum = mfma16(pf1, ones, lsum);
        #pragma unroll
        for (int t = 0; t < 4; t++) {
            int vrow = t * 16 + l16;
            int swz = vrow & 7;
            bf8 vb0 = *(const bf8*)(V + vrow * 64 + (quad ^ swz) * 8);
            bf8 vb1 = *(const bf8*)(V + vrow * 64 + (((quad + 4) ^ swz)) * 8);
            o[t] = mfma16(pf0, vb0, o[t]);
            o[t] = mfma16(pf1, vb1, o[t]);
        }
    };

    stage(0);

    for (int jt = 0; jt < ntiles; jt++) {
        __syncthreads();                       // drains vmcnt -> buf[jt&1] ready
        if (jt + 1 < ntiles) stage(jt + 1);
        const short* K = &Ks[jt & 1][0];
        const short* V = &Vs[jt & 1][0];
        int j0 = jt * 64;
        proc(qb_0, qb_1, rowbaseB, j0, K, V, ob, lsb);          // B: all tiles
        if (jt <= x)
            proc(qa_0, qa_1, rowbaseA, j0, K, V, oa, lsa);      // A: tiles 0..x
    }

    {
        float r0 = 1.0f / lsa[0], r1 = 1.0f / lsa[1], r2 = 1.0f / lsa[2], r3 = 1.0f / lsa[3];
        #pragma unroll
        for (int t = 0; t < 4; t++) {
            size_t base = (size_t)(b * SEQ + rowbaseA) * (NH * DV) + h * DV + t * 16 + l16;
            yg[base]                 = f2bf(oa[t][0] * r0);
            yg[base + 1 * (NH * DV)] = f2bf(oa[t][1] * r1);
            yg[base + 2 * (NH * DV)] = f2bf(oa[t][2] * r2);
            yg[base + 3 * (NH * DV)] = f2bf(oa[t][3] * r3);
        }
    }
    {
        float r0 = 1.0f / lsb[0], r1 = 1.0f / lsb[1], r2 = 1.0f / lsb[2], r3 = 1.0f / lsb[3];
        #pragma unroll
        for (int t = 0; t < 4; t++) {
            size_t base = (size_t)(b * SEQ + rowbaseB) * (NH * DV) + h * DV + t * 16 + l16;
            yg[base]                 = f2bf(ob[t][0] * r0);
            yg[base + 1 * (NH * DV)] = f2bf(ob[t][1] * r1);
            yg[base + 2 * (NH * DV)] = f2bf(ob[t][2] * r2);
            yg[base + 3 * (NH * DV)] = f2bf(ob[t][3] * r3);
        }
    }
}

// ---------------- launch ----------------

extern "C" void kernel_launch(void* const* d_in, const int* in_sizes, int n_in,
                              void* d_out, int out_size, void* d_ws, size_t ws_size,
                              hipStream_t stream) {
    const float* x    = (const float*)d_in[0];
    const float* w_q  = (const float*)d_in[1];
    const float* w_kv = (const float*)d_in[2];
    const float* w_o  = (const float*)d_in[3];
    const float* kw   = (const float*)d_in[4];
    float* out = (float*)d_out;

    char* ws = (char*)d_ws;
    short* xb    = (short*)(ws);                        // 4096x1024 bf16 : 8 MB
    short* wqkvt = (short*)(ws + ( 8u << 20));          // 2048x1024 bf16 : 4 MB
    short* wot   = (short*)(ws + (12u << 20));          // 1024x1024 bf16 : 2 MB
    short* qp    = (short*)(ws + (14u << 20));          // q' [4096][1024] : 8 MB
    short* kvb   = (short*)(ws + (22u << 20));          // kv [4096][1024] : 8 MB
    short* kvT   = (short*)(ws + (30u << 20));          // kvT [64bh*64v][1024 l] : 8 MB
    short* yb    = (short*)(ws + (38u << 20));          // y  [4096][1024] : 8 MB

    // x -> bf16
    cvt_x_kernel<<<4096, 256, 0, stream>>>(x, xb);
    // weights -> transposed bf16 (fused, grid.z = which weight)
    transpose_w_kernel<<<dim3(32, 32, 3), dim3(32, 8), 0, stream>>>(w_q, w_kv, w_o, wqkvt, wot);

    // projections: M=4096, N=2048, K=1024 -> q' (kw folded), kv, kvT (LDS-transposed)
    gemm_proj_kernel<<<dim3(16, 32), 256, 0, stream>>>(
        xb, wqkvt, kw, qp, kvb, kvT);

    // attention (pair-balanced, 2-wave blocks, double-buffered, reduction-free)
    attn_kernel<<<dim3(16, BATCH * NH), 128, 0, stream>>>(qp, kvb, kvT, yb);

    // output: M=4096, N=1024, K=1024 (64x128 tiles, BK=32, 512 blocks)
    gemm_out_kernel<<<dim3(8, 64), 256, 0, stream>>>(yb, wot, out);
}

// Round 11
// 158.370 us; speedup vs baseline: 1.0389x; 1.0389x over previous
//
#include <hip/hip_runtime.h>
#include <hip/hip_bf16.h>
#include <stdint.h>

#define BATCH 4
#define SEQ   1024
#define DMODEL 1024
#define NH    16
#define DV    64

typedef short bf8 __attribute__((ext_vector_type(8)));   // 8 bf16 raw bits = 4 VGPRs
typedef float f4  __attribute__((ext_vector_type(4)));

static __device__ __forceinline__ short f2bf(float f) {
    union { float f; uint32_t u; } a; a.f = f;
    uint32_t r = a.u + 0x7FFF + ((a.u >> 16) & 1);   // RNE
    return (short)(r >> 16);
}

static __device__ __forceinline__ f4 mfma16(bf8 a, bf8 b, f4 c) {
    return __builtin_amdgcn_mfma_f32_16x16x32_bf16(a, b, c, 0, 0, 0);
}

// async global->LDS, 16B per lane; LDS dest is wave-uniform base + lane*16
static __device__ __forceinline__ void gload16(const short* g, short* l) {
    __builtin_amdgcn_global_load_lds((const __attribute__((address_space(1))) void*)g,
                                     (__attribute__((address_space(3))) void*)l,
                                     16, 0, 0);
}

// ---------------- conversion kernels ----------------

__global__ void cvt_x_kernel(const float* __restrict__ x, short* __restrict__ xb) {
    int i = blockIdx.x * blockDim.x + threadIdx.x;   // one short4 per thread
    float4 v = ((const float4*)x)[i];
    short4 o;
    o.x = f2bf(v.x); o.y = f2bf(v.y); o.z = f2bf(v.z); o.w = f2bf(v.w);
    ((short4*)xb)[i] = o;
}

// fused: z=0 w_q -> wqkvt[0:1024], z=1 w_kv -> wqkvt[1024:2048], z=2 w_o -> wot
__global__ void transpose_w_kernel(const float* __restrict__ wq, const float* __restrict__ wkv,
                                   const float* __restrict__ wo,
                                   short* __restrict__ wqkvt, short* __restrict__ wot) {
    __shared__ float tile[32][33];
    int z = blockIdx.z;
    const float* w = (z == 0) ? wq : (z == 1) ? wkv : wo;
    short* wt = (z == 0) ? wqkvt : (z == 1) ? (wqkvt + (1u << 20)) : wot;
    int bx = blockIdx.x, by = blockIdx.y;
    int tx = threadIdx.x, ty = threadIdx.y;          // block (32,8)
    #pragma unroll
    for (int i = 0; i < 4; i++)
        tile[ty + i * 8][tx] = w[(size_t)(by * 32 + ty + i * 8) * 1024 + bx * 32 + tx];
    __syncthreads();
    #pragma unroll
    for (int i = 0; i < 4; i++)
        wt[(size_t)(bx * 32 + ty + i * 8) * 1024 + by * 32 + tx] = f2bf(tile[tx][ty + i * 8]);
}

// ---------------- projection GEMM: xb (4096xK) * wqkvt^T, N=2048 --------------------
// 64x128 tile, BK=64 -> grid (16,64) = 1024 blocks = 4 blocks/CU (vs 2 at 128x128).
// Wave w owns rows wm=w*16, all 128 cols: 8 C-frags, 16 MFMAs/iter. LDS 24 KB.
// XOR-swizzle: 16B seg c of row r at phys c^(r&7) -> frag reads 2-way/free (m136).
// Epilogue: n<1024 -> q' (scaled, kw folded); n>=1024 -> kv row-major AND kvT via
// single-pass LDS transpose (T = 128n x 64m, 18 KB, reuses staging LDS).

__global__ __launch_bounds__(256) void gemm_proj_kernel(
    const short* __restrict__ A, const short* __restrict__ Bt,
    const float* __restrict__ kw,
    short* __restrict__ q_out, short* __restrict__ kv_out, short* __restrict__ kvT_out)
{
    __shared__ short SM[12288];      // As[0:4096] | Bs[4096:12288] = 24 KB; T reuse = 18 KB
    short* As = SM;
    short* Bs = SM + 4096;
    const int K = DMODEL;

    int tid = threadIdx.x;
    int wave = tid >> 6, lane = tid & 63;
    int quad = lane >> 4, l16 = lane & 15;
    int m0 = blockIdx.y * 64;
    int n0 = blockIdx.x * 128;
    int wm = wave * 16;
    int sw = l16 & 7;                // frag-read segment xor (row & 7)

    f4 acc[8] = {};

    for (int k0 = 0; k0 < K; k0 += 64) {
        __syncthreads();
        #pragma unroll
        for (int c = 0; c < 2; c++) {
            int flat = c * 256 + tid;                  // 0..511 -> A 64x64
            int row = flat >> 3;                       // 0..63
            int seg = (flat & 7) ^ (row & 7);
            gload16(A + (size_t)(m0 + row) * K + k0 + seg * 8, As + flat * 8);
        }
        #pragma unroll
        for (int c = 0; c < 4; c++) {
            int flat = c * 256 + tid;                  // 0..1023 -> B 128x64
            int row = flat >> 3;                       // 0..127
            int seg = (flat & 7) ^ (row & 7);
            gload16(Bt + (size_t)(n0 + row) * K + k0 + seg * 8, Bs + flat * 8);
        }
        __syncthreads();

        #pragma unroll
        for (int kk = 0; kk < 2; kk++) {
            bf8 af = *(const bf8*)(As + (wm + l16) * 64 + ((kk * 4 + quad) ^ sw) * 8);
            #pragma unroll
            for (int j = 0; j < 8; j++) {
                bf8 bf_ = *(const bf8*)(Bs + (j * 16 + l16) * 64 + ((kk * 4 + quad) ^ sw) * 8);
                acc[j] = mfma16(af, bf_, acc[j]);
            }
        }
    }

    // ---- direct epilogue: q' / kv row-major (block-uniform branch: n0 is 128-aligned) ----
    #pragma unroll
    for (int j = 0; j < 8; j++) {
        int n = n0 + j * 16 + l16;
        int mb = m0 + wm + quad * 4;
        float v0 = acc[j][0], v1 = acc[j][1], v2 = acc[j][2], v3 = acc[j][3];
        if (n < 1024) {
            float kws = 0.03125f * (1.0f + kw[n]);
            q_out[(size_t)(mb + 0) * 1024 + n] = f2bf(v0 * kws);
            q_out[(size_t)(mb + 1) * 1024 + n] = f2bf(v1 * kws);
            q_out[(size_t)(mb + 2) * 1024 + n] = f2bf(v2 * kws);
            q_out[(size_t)(mb + 3) * 1024 + n] = f2bf(v3 * kws);
        } else {
            int n2 = n - 1024;
            kv_out[(size_t)(mb + 0) * 1024 + n2] = f2bf(v0);
            kv_out[(size_t)(mb + 1) * 1024 + n2] = f2bf(v1);
            kv_out[(size_t)(mb + 2) * 1024 + n2] = f2bf(v2);
            kv_out[(size_t)(mb + 3) * 1024 + n2] = f2bf(v3);
        }
    }

    // ---- kvT via single-pass LDS transpose (kv column-blocks only) ----
    if (n0 >= 1024) {
        const int TST = 72;                 // T row stride (shorts): 144B, 16B-aligned
        short* T = SM;                      // 128 * 72 = 9216 shorts = 18 KB <= 24 KB
        int n2base = n0 - 1024;
        int mloc = m0 & 1023;               // column base within the 1024-long kvT row
        int bq = m0 >> 10;                  // batch index (uniform across the tile)
        __syncthreads();                    // staging LDS reads complete before overwrite
        #pragma unroll
        for (int j = 0; j < 8; j++) {       // T[n][m] = acc
            int nl = j * 16 + l16;                        // 0..127
            short4 tv;
            tv.x = f2bf(acc[j][0]); tv.y = f2bf(acc[j][1]);
            tv.z = f2bf(acc[j][2]); tv.w = f2bf(acc[j][3]);
            *(short4*)(T + nl * TST + wm + quad * 4) = tv;
        }
        __syncthreads();
        // cooperative coalesced store: 128 rows x 64 m-shorts = 1024 x 16B units
        #pragma unroll
        for (int c = 0; c < 4; c++) {
            int flat = c * 256 + tid;       // 0..1023
            int row = flat >> 3;            // 0..127 (n within tile)
            int seg = flat & 7;             // 16B unit within 128B row
            bf8 vseg = *(const bf8*)(T + row * TST + seg * 8);
            int n2 = n2base + row;
            int bh = (bq << 4) + (n2 >> 6);
            *(bf8*)(kvT_out + (size_t)(bh * 64 + (n2 & 63)) * 1024 + mloc + seg * 8) = vseg;
        }
    }
}

// ---------------- output GEMM: yb (4096xK) * wot^T, N=1024 --------------------------
// 64x128 tile, BK=64 -> 512 blocks (2/CU). 8 C-frags, 16 MFMAs/iter. LDS 24 KB.

__global__ __launch_bounds__(256) void gemm_out_kernel(
    const short* __restrict__ A, const short* __restrict__ Bt,
    float* __restrict__ c_out)
{
    __shared__ short As[64 * 64];    // 8 KB
    __shared__ short Bs[128 * 64];   // 16 KB
    const int K = DMODEL;

    int tid = threadIdx.x;
    int wave = tid >> 6, lane = tid & 63;
    int quad = lane >> 4, l16 = lane & 15;
    int m0 = blockIdx.y * 64;
    int n0 = blockIdx.x * 128;
    int wm = wave * 16;
    int sw = l16 & 7;

    f4 acc[8] = {};

    for (int k0 = 0; k0 < K; k0 += 64) {
        __syncthreads();
        #pragma unroll
        for (int c = 0; c < 2; c++) {
            int flat = c * 256 + tid;                  // 0..511
            int row = flat >> 3;                       // 0..63
            int seg = (flat & 7) ^ (row & 7);
            gload16(A + (size_t)(m0 + row) * K + k0 + seg * 8, As + flat * 8);
        }
        #pragma unroll
        for (int c = 0; c < 4; c++) {
            int flat = c * 256 + tid;                  // 0..1023
            int row = flat >> 3;                       // 0..127
            int seg = (flat & 7) ^ (row & 7);
            gload16(Bt + (size_t)(n0 + row) * K + k0 + seg * 8, Bs + flat * 8);
        }
        __syncthreads();

        #pragma unroll
        for (int kk = 0; kk < 2; kk++) {
            bf8 af = *(const bf8*)(As + (wm + l16) * 64 + ((kk * 4 + quad) ^ sw) * 8);
            #pragma unroll
            for (int j = 0; j < 8; j++) {
                bf8 bf_ = *(const bf8*)(Bs + (j * 16 + l16) * 64 + ((kk * 4 + quad) ^ sw) * 8);
                acc[j] = mfma16(af, bf_, acc[j]);
            }
        }
    }

    #pragma unroll
    for (int j = 0; j < 8; j++) {
        int n = n0 + j * 16 + l16;
        int mb = m0 + wm + quad * 4;
        c_out[(size_t)(mb + 0) * 1024 + n] = acc[j][0];
        c_out[(size_t)(mb + 1) * 1024 + n] = acc[j][1];
        c_out[(size_t)(mb + 2) * 1024 + n] = acc[j][2];
        c_out[(size_t)(mb + 3) * 1024 + n] = acc[j][3];
    }
}

// ---------------- flash attention (causal), pair-balanced, 1 barrier/tile ----------
// Block x in [0,8) handles q-tiles A=x and B=15-x (64 rows each): every block does
// exactly 17 tile-computes over 16-x staged K/V tiles -- balanced causal load.
// K/V staged via global_load_lds (XOR-swizzled), double-buffered, one __syncthreads
// per tile. exp without max-subtraction (logits bounded by construction); row-sums
// via MFMA vs all-ones; per-wave private P (no barrier).

#define PLD 72   // P row stride (shorts)

__global__ __launch_bounds__(256) void attn_kernel(
    const short* __restrict__ qg, const short* __restrict__ kvg,
    const short* __restrict__ kvTg, short* __restrict__ yg)
{
    int bh = blockIdx.y;
    int b = bh >> 4, h = bh & 15;
    int x = blockIdx.x;
    int tid = threadIdx.x;
    int wave = tid >> 6, lane = tid & 63;
    int quad = lane >> 4, l16 = lane & 15;
    int qa0 = x * 64;
    int qb0 = (15 - x) * 64;
    int ntiles = 16 - x;

    __shared__ short Ks[2][64 * 64];    // [key][ch], swizzled, 8 KB each
    __shared__ short Vs[2][64 * 64];    // [vcol][key], swizzled
    __shared__ short Ps[4][16 * PLD];
    short* myP = &Ps[wave][0];

    const short* qpa = qg + (size_t)(b * 1024 + qa0 + wave * 16 + l16) * 1024 + h * 64;
    const short* qpb = qg + (size_t)(b * 1024 + qb0 + wave * 16 + l16) * 1024 + h * 64;
    bf8 qa_0 = *(const bf8*)(qpa + quad * 8);
    bf8 qa_1 = *(const bf8*)(qpa + 32 + quad * 8);
    bf8 qb_0 = *(const bf8*)(qpb + quad * 8);
    bf8 qb_1 = *(const bf8*)(qpb + 32 + quad * 8);

    bf8 ones;
    #pragma unroll
    for (int j = 0; j < 8; j++) ones[j] = (short)0x3F80;   // bf16 1.0

    f4 oa[4] = {}, ob[4] = {};
    f4 lsa = {}, lsb = {};
    int rowbaseA = qa0 + wave * 16 + quad * 4;
    int rowbaseB = qb0 + wave * 16 + quad * 4;

    auto stage = [&](int jt) {
        short* dstK = &Ks[jt & 1][0];
        short* dstV = &Vs[jt & 1][0];
        int j0 = jt * 64;
        #pragma unroll
        for (int k = 0; k < 2; k++) {
            int flat = k * 256 + tid;
            int row = flat >> 3;
            int lseg = (flat & 7) ^ (row & 7);
            gload16(kvg + (size_t)(b * 1024 + j0 + row) * 1024 + h * 64 + lseg * 8,
                    dstK + flat * 8);
            gload16(kvTg + (size_t)(bh * 64 + row) * 1024 + j0 + lseg * 8,
                    dstV + flat * 8);
        }
    };

    auto proc = [&](bf8 qf0, bf8 qf1, int rowbase, int j0,
                    const short* K, const short* V, f4 (&o)[4], f4& lsum) {
        f4 s[4];
        #pragma unroll
        for (int c = 0; c < 4; c++) {
            int row = c * 16 + l16;
            int swz = row & 7;
            bf8 kb0 = *(const bf8*)(K + row * 64 + (quad ^ swz) * 8);
            bf8 kb1 = *(const bf8*)(K + row * 64 + (((quad + 4) ^ swz)) * 8);
            f4 t = {};
            t = mfma16(qf0, kb0, t);
            t = mfma16(qf1, kb1, t);
            s[c] = t;
        }
        #pragma unroll
        for (int r = 0; r < 4; r++) {
            int qi = rowbase + r;
            float p0 = (j0 + l16      <= qi) ? __expf(s[0][r]) : 0.0f;
            float p1 = (j0 + 16 + l16 <= qi) ? __expf(s[1][r]) : 0.0f;
            float p2 = (j0 + 32 + l16 <= qi) ? __expf(s[2][r]) : 0.0f;
            float p3 = (j0 + 48 + l16 <= qi) ? __expf(s[3][r]) : 0.0f;
            int prow = quad * 4 + r;
            myP[prow * PLD + l16]      = f2bf(p0);
            myP[prow * PLD + 16 + l16] = f2bf(p1);
            myP[prow * PLD + 32 + l16] = f2bf(p2);
            myP[prow * PLD + 48 + l16] = f2bf(p3);
        }
        bf8 pf0 = *(const bf8*)(myP + l16 * PLD + quad * 8);
        bf8 pf1 = *(const bf8*)(myP + l16 * PLD + 32 + quad * 8);
        lsum = mfma16(pf0, ones, lsum);
        lsum = mfma16(pf1, ones, lsum);
        #pragma unroll
        for (int t = 0; t < 4; t++) {
            int vrow = t * 16 + l16;
            int swz = vrow & 7;
            bf8 vb0 = *(const bf8*)(V + vrow * 64 + (quad ^ swz) * 8);
            bf8 vb1 = *(const bf8*)(V + vrow * 64 + (((quad + 4) ^ swz)) * 8);
            o[t] = mfma16(pf0, vb0, o[t]);
            o[t] = mfma16(pf1, vb1, o[t]);
        }
    };

    stage(0);

    for (int jt = 0; jt < ntiles; jt++) {
        __syncthreads();                       // drains vmcnt -> buf[jt&1] ready
        if (jt + 1 < ntiles) stage(jt + 1);
        const short* K = &Ks[jt & 1][0];
        const short* V = &Vs[jt & 1][0];
        int j0 = jt * 64;
        proc(qb_0, qb_1, rowbaseB, j0, K, V, ob, lsb);          // B: all tiles
        if (jt <= x)
            proc(qa_0, qa_1, rowbaseA, j0, K, V, oa, lsa);      // A: tiles 0..x
    }

    {
        float r0 = 1.0f / lsa[0], r1 = 1.0f / lsa[1], r2 = 1.0f / lsa[2], r3 = 1.0f / lsa[3];
        #pragma unroll
        for (int t = 0; t < 4; t++) {
            size_t base = (size_t)(b * SEQ + rowbaseA) * (NH * DV) + h * DV + t * 16 + l16;
            yg[base]                 = f2bf(oa[t][0] * r0);
            yg[base + 1 * (NH * DV)] = f2bf(oa[t][1] * r1);
            yg[base + 2 * (NH * DV)] = f2bf(oa[t][2] * r2);
            yg[base + 3 * (NH * DV)] = f2bf(oa[t][3] * r3);
        }
    }
    {
        float r0 = 1.0f / lsb[0], r1 = 1.0f / lsb[1], r2 = 1.0f / lsb[2], r3 = 1.0f / lsb[3];
        #pragma unroll
        for (int t = 0; t < 4; t++) {
            size_t base = (size_t)(b * SEQ + rowbaseB) * (NH * DV) + h * DV + t * 16 + l16;
            yg[base]                 = f2bf(ob[t][0] * r0);
            yg[base + 1 * (NH * DV)] = f2bf(ob[t][1] * r1);
            yg[base + 2 * (NH * DV)] = f2bf(ob[t][2] * r2);
            yg[base + 3 * (NH * DV)] = f2bf(ob[t][3] * r3);
        }
    }
}

// ---------------- launch ----------------

extern "C" void kernel_launch(void* const* d_in, const int* in_sizes, int n_in,
                              void* d_out, int out_size, void* d_ws, size_t ws_size,
                              hipStream_t stream) {
    const float* x    = (const float*)d_in[0];
    const float* w_q  = (const float*)d_in[1];
    const float* w_kv = (const float*)d_in[2];
    const float* w_o  = (const float*)d_in[3];
    const float* kw   = (const float*)d_in[4];
    float* out = (float*)d_out;

    char* ws = (char*)d_ws;
    short* xb    = (short*)(ws);                        // 4096x1024 bf16 : 8 MB
    short* wqkvt = (short*)(ws + ( 8u << 20));          // 2048x1024 bf16 : 4 MB
    short* wot   = (short*)(ws + (12u << 20));          // 1024x1024 bf16 : 2 MB
    short* qp    = (short*)(ws + (14u << 20));          // q' [4096][1024] : 8 MB
    short* kvb   = (short*)(ws + (22u << 20));          // kv [4096][1024] : 8 MB
    short* kvT   = (short*)(ws + (30u << 20));          // kvT [64bh*64v][1024 l] : 8 MB
    short* yb    = (short*)(ws + (38u << 20));          // y  [4096][1024] : 8 MB

    // x -> bf16
    cvt_x_kernel<<<4096, 256, 0, stream>>>(x, xb);
    // weights -> transposed bf16 (fused, grid.z = which weight)
    transpose_w_kernel<<<dim3(32, 32, 3), dim3(32, 8), 0, stream>>>(w_q, w_kv, w_o, wqkvt, wot);

    // projections: M=4096, N=2048, K=1024 -> q' (kw folded), kv, kvT (LDS-transposed)
    // 64x128 tiles, 1024 blocks = 4 blocks/CU
    gemm_proj_kernel<<<dim3(16, 64), 256, 0, stream>>>(
        xb, wqkvt, kw, qp, kvb, kvT);

    // attention (pair-balanced, 4-wave blocks, double-buffered, reduction-free)
    attn_kernel<<<dim3(8, BATCH * NH), 256, 0, stream>>>(qp, kvb, kvT, yb);

    // output: M=4096, N=1024, K=1024 (64x128 tiles, BK=64, 512 blocks)
    gemm_out_kernel<<<dim3(8, 64), 256, 0, stream>>>(yb, wot, out);
}

// Round 12
// 157.550 us; speedup vs baseline: 1.0443x; 1.0052x over previous
//
#include <hip/hip_runtime.h>
#include <hip/hip_bf16.h>
#include <stdint.h>

#define BATCH 4
#define SEQ   1024
#define DMODEL 1024
#define NH    16
#define DV    64

typedef short bf8 __attribute__((ext_vector_type(8)));   // 8 bf16 raw bits = 4 VGPRs
typedef float f4  __attribute__((ext_vector_type(4)));

static __device__ __forceinline__ short f2bf(float f) {
    union { float f; uint32_t u; } a; a.f = f;
    uint32_t r = a.u + 0x7FFF + ((a.u >> 16) & 1);   // RNE
    return (short)(r >> 16);
}

static __device__ __forceinline__ f4 mfma16(bf8 a, bf8 b, f4 c) {
    return __builtin_amdgcn_mfma_f32_16x16x32_bf16(a, b, c, 0, 0, 0);
}

// async global->LDS, 16B per lane; LDS dest is wave-uniform base + lane*16
static __device__ __forceinline__ void gload16(const short* g, short* l) {
    __builtin_amdgcn_global_load_lds((const __attribute__((address_space(1))) void*)g,
                                     (__attribute__((address_space(3))) void*)l,
                                     16, 0, 0);
}

// ---------------- prep kernel: weight transposes + x conversion, one launch ---------
// grid (32,32,7), block (32,8). z<3: transpose w_z (fp32->bf16 Wt). z>=3: cvt slice.

__global__ void prep_kernel(const float* __restrict__ x,
                            const float* __restrict__ wq, const float* __restrict__ wkv,
                            const float* __restrict__ wo,
                            short* __restrict__ xb,
                            short* __restrict__ wqkvt, short* __restrict__ wot) {
    int z = blockIdx.z;
    int tx = threadIdx.x, ty = threadIdx.y;          // (32,8)
    if (z >= 3) {
        // cvt slice z-3: 1024 blocks x 256 threads x 1 float4
        int i = (((z - 3) * 1024 + blockIdx.y * 32 + blockIdx.x) << 8) + ty * 32 + tx;
        float4 v = ((const float4*)x)[i];
        short4 o;
        o.x = f2bf(v.x); o.y = f2bf(v.y); o.z = f2bf(v.z); o.w = f2bf(v.w);
        ((short4*)xb)[i] = o;
        return;
    }
    __shared__ float tile[32][33];
    const float* w = (z == 0) ? wq : (z == 1) ? wkv : wo;
    short* wt = (z == 0) ? wqkvt : (z == 1) ? (wqkvt + (1u << 20)) : wot;
    int bx = blockIdx.x, by = blockIdx.y;
    #pragma unroll
    for (int i = 0; i < 4; i++)
        tile[ty + i * 8][tx] = w[(size_t)(by * 32 + ty + i * 8) * 1024 + bx * 32 + tx];
    __syncthreads();
    #pragma unroll
    for (int i = 0; i < 4; i++)
        wt[(size_t)(bx * 32 + ty + i * 8) * 1024 + by * 32 + tx] = f2bf(tile[tx][ty + i * 8]);
}

// ---------------- projection GEMM: xb (4096xK) * wqkvt^T, N=2048 --------------------
// 64x128 tile, BK=64, grid (16,64) = 1024 blocks = 4 blocks/CU. 8 C-frags/wave,
// 16 MFMAs/iter. XOR-swizzle LDS (seg c of row r at phys c^(r&7)) -> 2-way/free.
// Epilogue: n<1024 -> q' (scaled, kw folded); n>=1024 -> kv row-major AND kvT via
// single-pass LDS transpose.

__global__ __launch_bounds__(256) void gemm_proj_kernel(
    const short* __restrict__ A, const short* __restrict__ Bt,
    const float* __restrict__ kw,
    short* __restrict__ q_out, short* __restrict__ kv_out, short* __restrict__ kvT_out)
{
    __shared__ short SM[12288];      // As[0:4096] | Bs[4096:12288] = 24 KB; T reuse = 18 KB
    short* As = SM;
    short* Bs = SM + 4096;
    const int K = DMODEL;

    int tid = threadIdx.x;
    int wave = tid >> 6, lane = tid & 63;
    int quad = lane >> 4, l16 = lane & 15;
    int m0 = blockIdx.y * 64;
    int n0 = blockIdx.x * 128;
    int wm = wave * 16;
    int sw = l16 & 7;                // frag-read segment xor (row & 7)

    f4 acc[8] = {};

    for (int k0 = 0; k0 < K; k0 += 64) {
        __syncthreads();
        #pragma unroll
        for (int c = 0; c < 2; c++) {
            int flat = c * 256 + tid;                  // 0..511 -> A 64x64
            int row = flat >> 3;                       // 0..63
            int seg = (flat & 7) ^ (row & 7);
            gload16(A + (size_t)(m0 + row) * K + k0 + seg * 8, As + flat * 8);
        }
        #pragma unroll
        for (int c = 0; c < 4; c++) {
            int flat = c * 256 + tid;                  // 0..1023 -> B 128x64
            int row = flat >> 3;                       // 0..127
            int seg = (flat & 7) ^ (row & 7);
            gload16(Bt + (size_t)(n0 + row) * K + k0 + seg * 8, Bs + flat * 8);
        }
        __syncthreads();

        #pragma unroll
        for (int kk = 0; kk < 2; kk++) {
            bf8 af = *(const bf8*)(As + (wm + l16) * 64 + ((kk * 4 + quad) ^ sw) * 8);
            #pragma unroll
            for (int j = 0; j < 8; j++) {
                bf8 bf_ = *(const bf8*)(Bs + (j * 16 + l16) * 64 + ((kk * 4 + quad) ^ sw) * 8);
                acc[j] = mfma16(af, bf_, acc[j]);
            }
        }
    }

    // ---- direct epilogue: q' / kv row-major (block-uniform branch: n0 is 128-aligned) ----
    #pragma unroll
    for (int j = 0; j < 8; j++) {
        int n = n0 + j * 16 + l16;
        int mb = m0 + wm + quad * 4;
        float v0 = acc[j][0], v1 = acc[j][1], v2 = acc[j][2], v3 = acc[j][3];
        if (n < 1024) {
            float kws = 0.03125f * (1.0f + kw[n]);
            q_out[(size_t)(mb + 0) * 1024 + n] = f2bf(v0 * kws);
            q_out[(size_t)(mb + 1) * 1024 + n] = f2bf(v1 * kws);
            q_out[(size_t)(mb + 2) * 1024 + n] = f2bf(v2 * kws);
            q_out[(size_t)(mb + 3) * 1024 + n] = f2bf(v3 * kws);
        } else {
            int n2 = n - 1024;
            kv_out[(size_t)(mb + 0) * 1024 + n2] = f2bf(v0);
            kv_out[(size_t)(mb + 1) * 1024 + n2] = f2bf(v1);
            kv_out[(size_t)(mb + 2) * 1024 + n2] = f2bf(v2);
            kv_out[(size_t)(mb + 3) * 1024 + n2] = f2bf(v3);
        }
    }

    // ---- kvT via single-pass LDS transpose (kv column-blocks only) ----
    if (n0 >= 1024) {
        const int TST = 72;                 // T row stride (shorts): 144B, 16B-aligned
        short* T = SM;                      // 128 * 72 = 9216 shorts = 18 KB <= 24 KB
        int n2base = n0 - 1024;
        int mloc = m0 & 1023;               // column base within the 1024-long kvT row
        int bq = m0 >> 10;                  // batch index (uniform across the tile)
        __syncthreads();                    // staging LDS reads complete before overwrite
        #pragma unroll
        for (int j = 0; j < 8; j++) {       // T[n][m] = acc
            int nl = j * 16 + l16;                        // 0..127
            short4 tv;
            tv.x = f2bf(acc[j][0]); tv.y = f2bf(acc[j][1]);
            tv.z = f2bf(acc[j][2]); tv.w = f2bf(acc[j][3]);
            *(short4*)(T + nl * TST + wm + quad * 4) = tv;
        }
        __syncthreads();
        // cooperative coalesced store: 128 rows x 64 m-shorts = 1024 x 16B units
        #pragma unroll
        for (int c = 0; c < 4; c++) {
            int flat = c * 256 + tid;       // 0..1023
            int row = flat >> 3;            // 0..127 (n within tile)
            int seg = flat & 7;             // 16B unit within 128B row
            bf8 vseg = *(const bf8*)(T + row * TST + seg * 8);
            int n2 = n2base + row;
            int bh = (bq << 4) + (n2 >> 6);
            *(bf8*)(kvT_out + (size_t)(bh * 64 + (n2 & 63)) * 1024 + mloc + seg * 8) = vseg;
        }
    }
}

// ---------------- output GEMM: yb (4096xK) * wot^T, N=1024 --------------------------
// 64x128 tile, BK=64 -> 512 blocks (2/CU). 8 C-frags, 16 MFMAs/iter. LDS 24 KB.

__global__ __launch_bounds__(256) void gemm_out_kernel(
    const short* __restrict__ A, const short* __restrict__ Bt,
    float* __restrict__ c_out)
{
    __shared__ short As[64 * 64];    // 8 KB
    __shared__ short Bs[128 * 64];   // 16 KB
    const int K = DMODEL;

    int tid = threadIdx.x;
    int wave = tid >> 6, lane = tid & 63;
    int quad = lane >> 4, l16 = lane & 15;
    int m0 = blockIdx.y * 64;
    int n0 = blockIdx.x * 128;
    int wm = wave * 16;
    int sw = l16 & 7;

    f4 acc[8] = {};

    for (int k0 = 0; k0 < K; k0 += 64) {
        __syncthreads();
        #pragma unroll
        for (int c = 0; c < 2; c++) {
            int flat = c * 256 + tid;                  // 0..511
            int row = flat >> 3;                       // 0..63
            int seg = (flat & 7) ^ (row & 7);
            gload16(A + (size_t)(m0 + row) * K + k0 + seg * 8, As + flat * 8);
        }
        #pragma unroll
        for (int c = 0; c < 4; c++) {
            int flat = c * 256 + tid;                  // 0..1023
            int row = flat >> 3;                       // 0..127
            int seg = (flat & 7) ^ (row & 7);
            gload16(Bt + (size_t)(n0 + row) * K + k0 + seg * 8, Bs + flat * 8);
        }
        __syncthreads();

        #pragma unroll
        for (int kk = 0; kk < 2; kk++) {
            bf8 af = *(const bf8*)(As + (wm + l16) * 64 + ((kk * 4 + quad) ^ sw) * 8);
            #pragma unroll
            for (int j = 0; j < 8; j++) {
                bf8 bf_ = *(const bf8*)(Bs + (j * 16 + l16) * 64 + ((kk * 4 + quad) ^ sw) * 8);
                acc[j] = mfma16(af, bf_, acc[j]);
            }
        }
    }

    #pragma unroll
    for (int j = 0; j < 8; j++) {
        int n = n0 + j * 16 + l16;
        int mb = m0 + wm + quad * 4;
        c_out[(size_t)(mb + 0) * 1024 + n] = acc[j][0];
        c_out[(size_t)(mb + 1) * 1024 + n] = acc[j][1];
        c_out[(size_t)(mb + 2) * 1024 + n] = acc[j][2];
        c_out[(size_t)(mb + 3) * 1024 + n] = acc[j][3];
    }
}

// ---------------- flash attention (causal), pair-balanced, INTERLEAVED A/B ----------
// Block x in [0,8) handles q-tiles A=x and B=15-x. The two per-tile procs are
// independent: interleave stage-by-stage (QK_B|QK_A -> exp_B|exp_A -> PV_B|PV_A)
// with two private P buffers per wave, so each chain's exp/LDS latency is hidden by
// the other's MFMA work. One __syncthreads per K/V tile (double-buffered staging).
// exp without max-subtraction (logits bounded by construction); row-sums via MFMA
// vs all-ones.

#define PLD 72   // P row stride (shorts)

__global__ __launch_bounds__(256) void attn_kernel(
    const short* __restrict__ qg, const short* __restrict__ kvg,
    const short* __restrict__ kvTg, short* __restrict__ yg)
{
    int bh = blockIdx.y;
    int b = bh >> 4, h = bh & 15;
    int x = blockIdx.x;
    int tid = threadIdx.x;
    int wave = tid >> 6, lane = tid & 63;
    int quad = lane >> 4, l16 = lane & 15;
    int qa0 = x * 64;
    int qb0 = (15 - x) * 64;
    int ntiles = 16 - x;

    __shared__ short Ks[2][64 * 64];        // [key][ch], swizzled, 8 KB each
    __shared__ short Vs[2][64 * 64];        // [vcol][key], swizzled
    __shared__ short Ps[4][2 * 16 * PLD];   // two P buffers per wave
    short* myPB = &Ps[wave][0];
    short* myPA = &Ps[wave][16 * PLD];

    const short* qpa = qg + (size_t)(b * 1024 + qa0 + wave * 16 + l16) * 1024 + h * 64;
    const short* qpb = qg + (size_t)(b * 1024 + qb0 + wave * 16 + l16) * 1024 + h * 64;
    bf8 qa_0 = *(const bf8*)(qpa + quad * 8);
    bf8 qa_1 = *(const bf8*)(qpa + 32 + quad * 8);
    bf8 qb_0 = *(const bf8*)(qpb + quad * 8);
    bf8 qb_1 = *(const bf8*)(qpb + 32 + quad * 8);

    bf8 ones;
    #pragma unroll
    for (int j = 0; j < 8; j++) ones[j] = (short)0x3F80;   // bf16 1.0

    f4 oa[4] = {}, ob[4] = {};
    f4 lsa = {}, lsb = {};
    int rowbaseA = qa0 + wave * 16 + quad * 4;
    int rowbaseB = qb0 + wave * 16 + quad * 4;

    auto stage = [&](int jt) {
        short* dstK = &Ks[jt & 1][0];
        short* dstV = &Vs[jt & 1][0];
        int j0 = jt * 64;
        #pragma unroll
        for (int k = 0; k < 2; k++) {
            int flat = k * 256 + tid;
            int row = flat >> 3;
            int lseg = (flat & 7) ^ (row & 7);
            gload16(kvg + (size_t)(b * 1024 + j0 + row) * 1024 + h * 64 + lseg * 8,
                    dstK + flat * 8);
            gload16(kvTg + (size_t)(bh * 64 + row) * 1024 + j0 + lseg * 8,
                    dstV + flat * 8);
        }
    };

    auto qk = [&](bf8 qf0, bf8 qf1, const short* K, f4 (&s)[4]) {
        #pragma unroll
        for (int c = 0; c < 4; c++) {
            int row = c * 16 + l16;
            int swz = row & 7;
            bf8 kb0 = *(const bf8*)(K + row * 64 + (quad ^ swz) * 8);
            bf8 kb1 = *(const bf8*)(K + row * 64 + (((quad + 4) ^ swz)) * 8);
            f4 t = {};
            t = mfma16(qf0, kb0, t);
            t = mfma16(qf1, kb1, t);
            s[c] = t;
        }
    };

    auto expstore = [&](f4 (&s)[4], int rowbase, int j0, short* P) {
        #pragma unroll
        for (int r = 0; r < 4; r++) {
            int qi = rowbase + r;
            float p0 = (j0 + l16      <= qi) ? __expf(s[0][r]) : 0.0f;
            float p1 = (j0 + 16 + l16 <= qi) ? __expf(s[1][r]) : 0.0f;
            float p2 = (j0 + 32 + l16 <= qi) ? __expf(s[2][r]) : 0.0f;
            float p3 = (j0 + 48 + l16 <= qi) ? __expf(s[3][r]) : 0.0f;
            int prow = quad * 4 + r;
            P[prow * PLD + l16]      = f2bf(p0);
            P[prow * PLD + 16 + l16] = f2bf(p1);
            P[prow * PLD + 32 + l16] = f2bf(p2);
            P[prow * PLD + 48 + l16] = f2bf(p3);
        }
    };

    auto pv = [&](const short* P, const short* V, f4 (&o)[4], f4& lsum) {
        bf8 pf0 = *(const bf8*)(P + l16 * PLD + quad * 8);
        bf8 pf1 = *(const bf8*)(P + l16 * PLD + 32 + quad * 8);
        lsum = mfma16(pf0, ones, lsum);
        lsum = mfma16(pf1, ones, lsum);
        #pragma unroll
        for (int t = 0; t < 4; t++) {
            int vrow = t * 16 + l16;
            int swz = vrow & 7;
            bf8 vb0 = *(const bf8*)(V + vrow * 64 + (quad ^ swz) * 8);
            bf8 vb1 = *(const bf8*)(V + vrow * 64 + (((quad + 4) ^ swz)) * 8);
            o[t] = mfma16(pf0, vb0, o[t]);
            o[t] = mfma16(pf1, vb1, o[t]);
        }
    };

    stage(0);

    for (int jt = 0; jt < ntiles; jt++) {
        __syncthreads();                       // drains vmcnt -> buf[jt&1] ready
        if (jt + 1 < ntiles) stage(jt + 1);
        const short* K = &Ks[jt & 1][0];
        const short* V = &Vs[jt & 1][0];
        int j0 = jt * 64;
        bool doA = (jt <= x);

        f4 sb[4], sa[4];
        qk(qb_0, qb_1, K, sb);
        if (doA) qk(qa_0, qa_1, K, sa);
        expstore(sb, rowbaseB, j0, myPB);
        if (doA) expstore(sa, rowbaseA, j0, myPA);
        pv(myPB, V, ob, lsb);
        if (doA) pv(myPA, V, oa, lsa);
    }

    {
        float r0 = 1.0f / lsa[0], r1 = 1.0f / lsa[1], r2 = 1.0f / lsa[2], r3 = 1.0f / lsa[3];
        #pragma unroll
        for (int t = 0; t < 4; t++) {
            size_t base = (size_t)(b * SEQ + rowbaseA) * (NH * DV) + h * DV + t * 16 + l16;
            yg[base]                 = f2bf(oa[t][0] * r0);
            yg[base + 1 * (NH * DV)] = f2bf(oa[t][1] * r1);
            yg[base + 2 * (NH * DV)] = f2bf(oa[t][2] * r2);
            yg[base + 3 * (NH * DV)] = f2bf(oa[t][3] * r3);
        }
    }
    {
        float r0 = 1.0f / lsb[0], r1 = 1.0f / lsb[1], r2 = 1.0f / lsb[2], r3 = 1.0f / lsb[3];
        #pragma unroll
        for (int t = 0; t < 4; t++) {
            size_t base = (size_t)(b * SEQ + rowbaseB) * (NH * DV) + h * DV + t * 16 + l16;
            yg[base]                 = f2bf(ob[t][0] * r0);
            yg[base + 1 * (NH * DV)] = f2bf(ob[t][1] * r1);
            yg[base + 2 * (NH * DV)] = f2bf(ob[t][2] * r2);
            yg[base + 3 * (NH * DV)] = f2bf(ob[t][3] * r3);
        }
    }
}

// ---------------- launch ----------------

extern "C" void kernel_launch(void* const* d_in, const int* in_sizes, int n_in,
                              void* d_out, int out_size, void* d_ws, size_t ws_size,
                              hipStream_t stream) {
    const float* x    = (const float*)d_in[0];
    const float* w_q  = (const float*)d_in[1];
    const float* w_kv = (const float*)d_in[2];
    const float* w_o  = (const float*)d_in[3];
    const float* kw   = (const float*)d_in[4];
    float* out = (float*)d_out;

    char* ws = (char*)d_ws;
    short* xb    = (short*)(ws);                        // 4096x1024 bf16 : 8 MB
    short* wqkvt = (short*)(ws + ( 8u << 20));          // 2048x1024 bf16 : 4 MB
    short* wot   = (short*)(ws + (12u << 20));          // 1024x1024 bf16 : 2 MB
    short* qp    = (short*)(ws + (14u << 20));          // q' [4096][1024] : 8 MB
    short* kvb   = (short*)(ws + (22u << 20));          // kv [4096][1024] : 8 MB
    short* kvT   = (short*)(ws + (30u << 20));          // kvT [64bh*64v][1024 l] : 8 MB
    short* yb    = (short*)(ws + (38u << 20));          // y  [4096][1024] : 8 MB

    // weights transpose + x conversion, single launch
    prep_kernel<<<dim3(32, 32, 7), dim3(32, 8), 0, stream>>>(
        x, w_q, w_kv, w_o, xb, wqkvt, wot);

    // projections: M=4096, N=2048, K=1024 -> q' (kw folded), kv, kvT (LDS-transposed)
    gemm_proj_kernel<<<dim3(16, 64), 256, 0, stream>>>(
        xb, wqkvt, kw, qp, kvb, kvT);

    // attention (pair-balanced, interleaved A/B, double-buffered, reduction-free)
    attn_kernel<<<dim3(8, BATCH * NH), 256, 0, stream>>>(qp, kvb, kvT, yb);

    // output: M=4096, N=1024, K=1024 (64x128 tiles, BK=64, 512 blocks)
    gemm_out_kernel<<<dim3(8, 64), 256, 0, stream>>>(yb, wot, out);
}